// Round 3
// baseline (598.169 us; speedup 1.0000x reference)
//
#include <hip/hip_runtime.h>

// ---- problem constants -----------------------------------------------------
constexpr int N_ = 64, C_ = 64, T_ = 300, V_ = 25, IC_ = 16, S_ = 3, KT_ = 9;

// ---- tconv MFMA tiling ------------------------------------------------------
constexpr int TTM   = 12;               // t-steps per block (300 % 12 == 0)
constexpr int SROWS = TTM + 8;          // staged t rows (halo 4+4)
constexpr int MROWS = SROWS * V_;       // 500 staged patch rows
constexpr int XROWS = MROWS + 4;        // +4 pad rows for partial tile-18 reads
constexpr int CSTR  = 32;               // LDS row stride bf16 (32 data, XOR swizzle)
constexpr int NTB   = T_ / TTM;         // 25 t-blocks
constexpr int NTILE = (TTM * V_ + 15) / 16;  // 19 m-tiles of 16
constexpr int KS_   = 204;              // frag K stride (192 data + 12 pad)

// ---- agg_out MFMA tiling ----------------------------------------------------
constexpr int TTZ   = 16;               // t-steps per block
constexpr int NTBZ  = (T_ + TTZ - 1) / TTZ;  // 19
constexpr int ASTR  = 36;               // ags row stride (32 c + 4 pad), bf16

typedef __bf16 bf16x8 __attribute__((ext_vector_type(8)));
typedef __bf16 bf16x4 __attribute__((ext_vector_type(4)));
typedef float  f32x4  __attribute__((ext_vector_type(4)));

// ---- workspace layout (floats) ----------------------------------------------
constexpr int OFF_AFULL = 0;
constexpr int SZ_AFULL  = S_ * V_ * V_;                 // 1875
constexpr int OFF_WTB   = OFF_AFULL + SZ_AFULL;         // bf16 S*9*32*64
constexpr int SZ_WTB_F  = (S_ * KT_ * 32 * C_) / 2;     // 27648 float-slots
constexpr int OFF_BTC   = OFF_WTB + SZ_WTB_F;           // S*32 fp32 biases
constexpr int OFF_WDB   = OFF_BTC + S_ * 32;            // bf16 S*64*64 [i][o][c]
constexpr int SZ_WDB_F  = (S_ * C_ * C_) / 2;           // 6144 float-slots
constexpr int OFF_BDT   = OFF_WDB + SZ_WDB_F;           // C
constexpr int OFF_BNA   = OFF_BDT + C_;
constexpr int OFF_BNB   = OFF_BNA + C_;
constexpr int OFF_A1    = OFF_BNB + C_;
constexpr int SZ_A1     = S_ * N_ * V_ * V_;            // 120000  [i][n][u][v] fp32
constexpr int OFF_SACC  = OFF_A1 + SZ_A1;               // atomic S accumulator
constexpr int SZ_SACC   = S_ * N_ * V_ * V_;            // 120000 [i][n][u][v] fp32

// SlimConv2d channel scales: splits at int(0.6/0.7/0.8/0.9 * out_c)
__device__ __forceinline__ float slim16(const float* w, int o) {
    if (o < 9)  return 1.0f;
    if (o < 11) return w[1];
    if (o < 12) return w[2];
    if (o < 14) return w[3];
    return w[4];
}
__device__ __forceinline__ float slim64(const float* w, int o) {
    if (o < 38) return 1.0f;
    if (o < 44) return w[1];
    if (o < 51) return w[2];
    if (o < 57) return w[3];
    return w[4];
}

// ---- prep: A_full, packed bf16 weights, folded biases, BN affine, zero sacc -
__global__ void prep_kernel(const float* __restrict__ wv,  const float* __restrict__ A,
                            const float* __restrict__ PA,  const float* __restrict__ Wd,
                            const float* __restrict__ bd,  const float* __restrict__ WT1,
                            const float* __restrict__ bT1, const float* __restrict__ WT2,
                            const float* __restrict__ bT2, const float* __restrict__ gam,
                            const float* __restrict__ bet, const float* __restrict__ mu,
                            const float* __restrict__ var, float* __restrict__ ws)
{
    const int gid = blockIdx.x * blockDim.x + threadIdx.x;
    const int stride = gridDim.x * blockDim.x;
    // zero the atomic S accumulator
    for (int idx = gid; idx < SZ_SACC; idx += stride)
        ws[OFF_SACC + idx] = 0.f;
    // A_full = A + PA + 8A^4 - 4A^2 - 4A + I (elementwise powers)
    for (int idx = gid; idx < S_ * V_ * V_; idx += stride) {
        int uv = idx % (V_ * V_);
        int u = uv / V_, v = uv % V_;
        float a  = A[idx];
        float a2 = a * a;
        ws[OFF_AFULL + idx] = a + PA[idx] + 8.f * a2 * a2 - 4.f * a2 - 4.f * a
                              + (u == v ? 1.f : 0.f);
    }
    // t-conv weights: scaled bf16, layout [i][kt][o32][c]
    {
        __bf16* wtb = (__bf16*)(ws + OFF_WTB);
        for (int idx = gid; idx < S_ * KT_ * 32 * C_; idx += stride) {
            int c  = idx % C_;
            int r  = idx / C_;
            int o  = r % 32;  r /= 32;
            int kt = r % KT_;
            int i  = r / KT_;
            float val;
            if (o < IC_)
                val = slim16(wv, o) * WT1[((i * IC_ + o) * C_ + c) * KT_ + kt];
            else
                val = slim16(wv, o - IC_) * WT2[((i * IC_ + (o - IC_)) * C_ + c) * KT_ + kt];
            wtb[idx] = (__bf16)val;
        }
    }
    // combined scaled t-conv biases [i][o32]
    for (int idx = gid; idx < S_ * 32; idx += stride) {
        int i = idx / 32, o = idx % 32;
        float val = (o < IC_) ? slim16(wv, o) * bT1[i * IC_ + o]
                              : slim16(wv, o - IC_) * bT2[i * IC_ + (o - IC_)];
        ws[OFF_BTC + idx] = val;
    }
    // 1x1 conv weights: scaled bf16, [i][o][c] (B-frag layout for GEMM2)
    {
        __bf16* wdb = (__bf16*)(ws + OFF_WDB);
        for (int idx = gid; idx < S_ * C_ * C_; idx += stride) {
            int c = idx % C_;
            int o = (idx / C_) % C_;
            int i = idx / (C_ * C_);
            wdb[idx] = (__bf16)(slim64(wv, o) * Wd[(i * C_ + o) * C_ + c]);
        }
    }
    // summed scaled 1x1 bias + BN affine
    for (int idx = gid; idx < C_; idx += stride) {
        float bt = 0.f;
        for (int i = 0; i < S_; ++i) bt += slim64(wv, idx) * bd[i * C_ + idx];
        ws[OFF_BDT + idx] = bt;
        float ba = gam[idx] * rsqrtf(var[idx] + 1e-5f);
        ws[OFF_BNA + idx] = ba;
        ws[OFF_BNB + idx] = bet[idx] - mu[idx] * ba;
    }
}

// ---- kernel A: all 3 subsets' temporal convs + attention partials, fused ----
// Phase 1: implicit-GEMM conv via MFMA, x staged once (XOR-swizzled 16B groups).
// Phase 2 (per subset): acc (+bias, ->bf16) packed b64 into K-major LDS frags
//   (k = tl*16 + o, KS=204), then MFMA S[u,v] partial -> atomicAdd into sacc.
__global__ __launch_bounds__(320) void tconv_att_kernel(
    const float* __restrict__ x,  const __bf16* __restrict__ wt,
    const float* __restrict__ btc, float* __restrict__ sacc)
{
    __shared__ __align__(16) char lds_raw[XROWS * CSTR * 2];   // 32256 B
    __bf16* xs  = (__bf16*)lds_raw;                 // [504][32] conv staging
    __bf16* t1L = (__bf16*)lds_raw;                 // [32][KS_] S-stage (union)
    __bf16* t2L = t1L + 32 * KS_;
    const int tid  = threadIdx.x;
    const int n    = blockIdx.y;
    const int t0   = blockIdx.x * TTM;
    const int wv   = tid >> 6;
    const int lane = tid & 63;
    const int l15  = lane & 15;
    const int quad = lane >> 4;

    // zero the 4 pad rows (only read by discarded lanes of partial tile 18)
    if (tid < 16) {
        bf16x8 z;
#pragma unroll
        for (int jj = 0; jj < 8; ++jj) z[jj] = (__bf16)0.f;
        *(bf16x8*)&xs[(MROWS + (tid >> 2)) * CSTR + (tid & 3) * 8] = z;
    }

    f32x4 acc[4][6];
#pragma unroll
    for (int j = 0; j < 4; ++j)
#pragma unroll
        for (int p = 0; p < 6; ++p) acc[j][p] = (f32x4){0.f, 0.f, 0.f, 0.f};

    for (int ch = 0; ch < 2; ++ch) {
        const int c0 = ch * 32;
        __syncthreads();
        for (int idx = tid; idx < MROWS * 4; idx += 320) {
            const int lr = idx % MROWS;
            const int cg = idx / MROWS;
            const int tg = t0 - 4 + lr / V_;
            bf16x8 pk;
            if (tg >= 0 && tg < T_) {
                const float* gp = x + ((size_t)(n * C_ + c0 + cg * 8) * T_ + (t0 - 4)) * V_ + lr;
#pragma unroll
                for (int jj = 0; jj < 8; ++jj) pk[jj] = (__bf16)gp[(size_t)jj * T_ * V_];
            } else {
#pragma unroll
                for (int jj = 0; jj < 8; ++jj) pk[jj] = (__bf16)0.f;
            }
            *(bf16x8*)&xs[lr * CSTR + ((cg ^ (lr & 3)) << 3)] = pk;
        }
        __syncthreads();

        for (int kt = 0; kt < KT_; ++kt) {
            bf16x8 a[6];
#pragma unroll
            for (int p = 0; p < 6; ++p) {
                const int i = p >> 1, h = p & 1;
                a[p] = *(const bf16x8*)&wt[((size_t)((i * KT_ + kt) * 32 + h * 16 + l15)) * C_ + c0 + quad * 8];
            }
#pragma unroll
            for (int j = 0; j < 4; ++j) {
                const int jt = wv + 5 * j;
                if (jt < NTILE) {
                    const int r = jt * 16 + l15 + V_ * kt;
                    const bf16x8 b = *(const bf16x8*)&xs[r * CSTR + ((quad ^ (r & 3)) << 3)];
#pragma unroll
                    for (int p = 0; p < 6; ++p)
                        acc[j][p] = __builtin_amdgcn_mfma_f32_16x16x32_bf16(a[p], b, acc[j][p], 0, 0, 0);
                }
            }
        }
    }

    // ---- Phase 2: per-subset attention partial S[u,v] over this t-block ----
    for (int i = 0; i < S_; ++i) {
        __syncthreads();   // conv/frag LDS readers done
        // pack acc (+bias) -> K-major frags: t1L[u][tl*16+o], t2L[v][tl*16+o]
#pragma unroll
        for (int j = 0; j < 4; ++j) {
            const int jt = wv + 5 * j;
            if (jt < NTILE) {
                const int m = jt * 16 + l15;
                if (m < TTM * V_) {           // tile 18 is partial
                    const int tl = m / V_;
                    const int u  = m % V_;
#pragma unroll
                    for (int h = 0; h < 2; ++h) {
                        bf16x4 pk;
#pragma unroll
                        for (int r = 0; r < 4; ++r)
                            pk[r] = (__bf16)(acc[j][i * 2 + h][r] + btc[i * 32 + h * 16 + quad * 4 + r]);
                        __bf16* dst = (h ? t2L : t1L) + u * KS_ + tl * 16 + quad * 4;
                        *(bf16x4*)dst = pk;
                    }
                }
            }
        }
        __syncthreads();   // frags ready
        if (wv < 4) {
            const int ut = wv >> 1, vt = wv & 1;
            f32x4 sa = (f32x4){0.f, 0.f, 0.f, 0.f};
#pragma unroll
            for (int ks = 0; ks < 6; ++ks) {
                const bf16x8 A = *(const bf16x8*)&t1L[(ut * 16 + l15) * KS_ + ks * 32 + quad * 8];
                const bf16x8 B = *(const bf16x8*)&t2L[(vt * 16 + l15) * KS_ + ks * 32 + quad * 8];
                sa = __builtin_amdgcn_mfma_f32_16x16x32_bf16(A, B, sa, 0, 0, 0);
            }
            float* sp = sacc + ((size_t)i * N_ + n) * (V_ * V_);
#pragma unroll
            for (int r = 0; r < 4; ++r) {
                const int u = ut * 16 + quad * 4 + r;
                const int v = vt * 16 + l15;
                if (u < V_ && v < V_) atomicAdd(&sp[u * V_ + v], sa[r]);
            }
        }
    }
}

// ---- kernel B: scale, softmax over u (axis=-2), add A_full -----------------
__global__ __launch_bounds__(256) void att_softmax_kernel(
    const float* __restrict__ sacc, const float* __restrict__ afull,
    float* __restrict__ a1o)
{
    __shared__ float Ss[V_ * V_];
    const int n = blockIdx.x;
    const int i = blockIdx.y;
    const int tid = threadIdx.x;
    for (int p = tid; p < V_ * V_; p += 256)
        Ss[p] = sacc[((size_t)i * N_ + n) * (V_ * V_) + p] * (1.0f / (IC_ * T_));
    __syncthreads();
    if (tid < V_) {
        const int v = tid;
        float m = -1e30f;
#pragma unroll
        for (int u = 0; u < V_; ++u) m = fmaxf(m, Ss[u * V_ + v]);
        float e[V_]; float es = 0.f;
#pragma unroll
        for (int u = 0; u < V_; ++u) { e[u] = expf(Ss[u * V_ + v] - m); es += e[u]; }
        const float inv = 1.0f / es;
#pragma unroll
        for (int u = 0; u < V_; ++u)
            a1o[((size_t)i * N_ + n) * (V_ * V_) + u * V_ + v]
                = afull[i * (V_ * V_) + u * V_ + v] + e[u] * inv;
    }
}

// ---- kernel C: fused (x@A1_i)->1x1 conv via 2-stage MFMA, +BN+res+relu ------
__global__ __launch_bounds__(320) void agg_out_mfma_kernel(
    const float* __restrict__ x,   const float* __restrict__ a1,
    const __bf16* __restrict__ wdb, const float* __restrict__ bdt,
    const float* __restrict__ bna, const float* __restrict__ bnb,
    float* __restrict__ out)
{
    __shared__ __align__(16) __bf16 ags[400 * ASTR];      // 28.8 KB
    __shared__ __align__(16) __bf16 a1t3[S_ * 32 * 32];   // 6 KB [i][v32][u32]
    const int tid  = threadIdx.x;
    const int n    = blockIdx.y;
    const int t0   = blockIdx.x * TTZ;
    const int wv   = tid >> 6;
    const int lane = tid & 63;
    const int l15  = lane & 15;
    const int quad = lane >> 4;

    // stage A1^T for all 3 subsets once: a1t3[i][v][u], zero-padded
    for (int idx = tid; idx < S_ * 1024; idx += 320) {
        const int i = idx >> 10;
        const int r = idx & 1023;
        const int v = r >> 5, u = r & 31;
        float val = (v < V_ && u < V_)
                  ? a1[((size_t)(i * N_ + n) * V_ + u) * V_ + v] : 0.f;
        a1t3[idx] = (__bf16)val;
    }

    f32x4 acc[5][4];
#pragma unroll
    for (int j = 0; j < 5; ++j)
#pragma unroll
        for (int ot = 0; ot < 4; ++ot) acc[j][ot] = (f32x4){0.f, 0.f, 0.f, 0.f};

    const int tg = t0 + l15;                 // GEMM1 A-row (this lane's t)
    for (int chunk = 0; chunk < 2; ++chunk) {
        const int c0 = chunk * 32;
        // load & hold this wave's GEMM1 A-frags (x rows -> bf16), reused for all i
        bf16x8 afr[7];
#pragma unroll
        for (int k = 0; k < 7; ++k) {
            const int c = wv + 5 * k;
            bf16x8 pk;
#pragma unroll
            for (int jj = 0; jj < 8; ++jj) pk[jj] = (__bf16)0.f;
            if (c < 32 && tg < T_) {
                const float* gp = x + ((size_t)(n * C_ + c0 + c) * T_ + tg) * V_;
#pragma unroll
                for (int jj = 0; jj < 8; ++jj) {
                    const int u = quad * 8 + jj;
                    if (u < V_) pk[jj] = (__bf16)gp[u];
                }
            }
            afr[k] = pk;
        }
        for (int i = 0; i < S_; ++i) {
            __syncthreads();   // a1t3 ready (first pass) / prev GEMM2 done with ags
            const bf16x8 b0 = *(const bf16x8*)&a1t3[i * 1024 + l15 * 32 + quad * 8];
            const bf16x8 b1 = *(const bf16x8*)&a1t3[i * 1024 + (16 + l15) * 32 + quad * 8];
            // GEMM1: D row = t-local (quad*4+r), col = v (l15) -> scatter to ags[m2][c]
#pragma unroll
            for (int k = 0; k < 7; ++k) {
                const int c = wv + 5 * k;
                if (c < 32) {
                    f32x4 d0 = (f32x4){0.f, 0.f, 0.f, 0.f};
                    f32x4 d1 = (f32x4){0.f, 0.f, 0.f, 0.f};
                    d0 = __builtin_amdgcn_mfma_f32_16x16x32_bf16(afr[k], b0, d0, 0, 0, 0);
                    d1 = __builtin_amdgcn_mfma_f32_16x16x32_bf16(afr[k], b1, d1, 0, 0, 0);
#pragma unroll
                    for (int r = 0; r < 4; ++r) {
                        const int tl = quad * 4 + r;
                        ags[(tl * V_ + l15) * ASTR + c] = (__bf16)d0[r];
                        if (l15 < V_ - 16)
                            ags[(tl * V_ + 16 + l15) * ASTR + c] = (__bf16)d1[r];
                    }
                }
            }
            __syncthreads();   // ags ready
            // GEMM2: A = ags rows (m2 = l15-indexed), B = wdb (o = l15-indexed)
            bf16x8 bw[4];
#pragma unroll
            for (int ot = 0; ot < 4; ++ot)
                bw[ot] = *(const bf16x8*)&wdb[(size_t)(i * C_ + ot * 16 + l15) * C_ + c0 + quad * 8];
#pragma unroll
            for (int j = 0; j < 5; ++j) {
                const int m2 = (wv * 5 + j) * 16 + l15;
                const bf16x4 lo = *(const bf16x4*)&ags[m2 * ASTR + quad * 8];
                const bf16x4 hi = *(const bf16x4*)&ags[m2 * ASTR + quad * 8 + 4];
                const bf16x8 am = __builtin_shufflevector(lo, hi, 0, 1, 2, 3, 4, 5, 6, 7);
#pragma unroll
                for (int ot = 0; ot < 4; ++ot)
                    acc[j][ot] = __builtin_amdgcn_mfma_f32_16x16x32_bf16(am, bw[ot], acc[j][ot], 0, 0, 0);
            }
        }
    }

    // epilogue: D row = m2 local (quad*4+r consecutive), col = o (l15)
    const int mrem = (T_ - t0) * V_;   // valid m2 range in this t-block
#pragma unroll
    for (int ot = 0; ot < 4; ++ot) {
        const int o  = ot * 16 + l15;
        const float ba = bna[o], bb = bnb[o], bt = bdt[o];
#pragma unroll
        for (int j = 0; j < 5; ++j) {
            const int m2b = (wv * 5 + j) * 16 + quad * 4;
            if (m2b + 3 < mrem) {
                const size_t gi = (size_t)(n * C_ + o) * (T_ * V_) + (size_t)t0 * V_ + m2b;
                const f32x4 xr = *(const f32x4*)&x[gi];
                f32x4 rs;
#pragma unroll
                for (int r = 0; r < 4; ++r)
                    rs[r] = fmaxf(fmaf(acc[j][ot][r] + bt, ba, bb) + xr[r], 0.f);
                *(f32x4*)&out[gi] = rs;
            }
        }
    }
}

// ---- launch ----------------------------------------------------------------
extern "C" void kernel_launch(void* const* d_in, const int* in_sizes, int n_in,
                              void* d_out, int out_size, void* d_ws, size_t ws_size,
                              hipStream_t stream)
{
    (void)in_sizes; (void)n_in; (void)out_size; (void)ws_size;
    const float* x    = (const float*)d_in[0];
    const float* wv   = (const float*)d_in[1];
    const float* A    = (const float*)d_in[2];
    const float* PA   = (const float*)d_in[3];
    const float* Wd   = (const float*)d_in[4];
    const float* bd   = (const float*)d_in[5];
    const float* WT1  = (const float*)d_in[6];
    const float* bT1  = (const float*)d_in[7];
    const float* WT2  = (const float*)d_in[8];
    const float* bT2  = (const float*)d_in[9];
    const float* gam  = (const float*)d_in[10];
    const float* bet  = (const float*)d_in[11];
    const float* mu   = (const float*)d_in[12];
    const float* var  = (const float*)d_in[13];
    float* ws  = (float*)d_ws;
    float* out = (float*)d_out;

    prep_kernel<<<dim3(64), dim3(256), 0, stream>>>(
        wv, A, PA, Wd, bd, WT1, bT1, WT2, bT2, gam, bet, mu, var, ws);

    tconv_att_kernel<<<dim3(NTB, N_), dim3(320), 0, stream>>>(
        x, (const __bf16*)(ws + OFF_WTB), ws + OFF_BTC, ws + OFF_SACC);

    att_softmax_kernel<<<dim3(N_, S_), dim3(256), 0, stream>>>(
        ws + OFF_SACC, ws + OFF_AFULL, ws + OFF_A1);

    agg_out_mfma_kernel<<<dim3(NTBZ, N_), dim3(320), 0, stream>>>(
        x, ws + OFF_A1, (const __bf16*)(ws + OFF_WDB),
        ws + OFF_BDT, ws + OFF_BNA, ws + OFF_BNB, out);
}

// Round 5
// 568.820 us; speedup vs baseline: 1.0516x; 1.0516x over previous
//
#include <hip/hip_runtime.h>

// ---- problem constants -----------------------------------------------------
constexpr int N_ = 64, C_ = 64, T_ = 300, V_ = 25, IC_ = 16, S_ = 3, KT_ = 9;

// ---- x_t padded layout ------------------------------------------------------
constexpr int TP_   = T_ + 12;          // 312 t-rows: 4 zero front, 8 zero back
// x_t[n][tt][v][c] bf16, tt = t + 4. Stored in d_out scratch (63.9 MB < 122.9).

// ---- tconv MFMA tiling ------------------------------------------------------
constexpr int TTM   = 16;               // t-steps per block
constexpr int SROWS = TTM + 8;          // staged t rows (halo 4+4)
constexpr int MROWS = SROWS * V_;       // 600 staged patch rows
constexpr int CSTR  = 32;               // LDS row stride bf16 (linear, 64B rows)
constexpr int NTB   = (T_ + TTM - 1) / TTM;  // 19 t-blocks
constexpr int KS_   = 266;              // frag K stride bf16 (256 data, odd word stride)

// ---- agg_out MFMA tiling ----------------------------------------------------
constexpr int TTZ   = 16;               // t-steps per block
constexpr int NTBZ  = (T_ + TTZ - 1) / TTZ;  // 19
constexpr int ASTR  = 36;               // ags row stride (32 c + 4 pad), bf16

typedef __bf16 bf16x8 __attribute__((ext_vector_type(8)));
typedef __bf16 bf16x4 __attribute__((ext_vector_type(4)));
typedef float  f32x4  __attribute__((ext_vector_type(4)));

// ---- workspace layout (floats) ----------------------------------------------
constexpr int OFF_AFULL = 0;
constexpr int SZ_AFULL  = S_ * V_ * V_;                 // 1875
constexpr int OFF_WTB   = OFF_AFULL + SZ_AFULL;         // bf16 S*9*32*64
constexpr int SZ_WTB_F  = (S_ * KT_ * 32 * C_) / 2;     // 27648 float-slots
constexpr int OFF_BTC   = OFF_WTB + SZ_WTB_F;           // S*32 fp32 biases
constexpr int OFF_WDB   = OFF_BTC + S_ * 32;            // bf16 S*64*64 [i][o][c]
constexpr int SZ_WDB_F  = (S_ * C_ * C_) / 2;           // 6144 float-slots
constexpr int OFF_BDT   = OFF_WDB + SZ_WDB_F;           // C
constexpr int OFF_BNA   = OFF_BDT + C_;
constexpr int OFF_BNB   = OFF_BNA + C_;
constexpr int OFF_A1    = OFF_BNB + C_;
constexpr int SZ_A1     = S_ * N_ * V_ * V_;            // 120000  [i][n][u][v] fp32
constexpr int OFF_SACC  = OFF_A1 + SZ_A1;               // atomic S accumulator
constexpr int SZ_SACC   = S_ * N_ * V_ * V_;            // 120000 [i][n][u][v] fp32

// SlimConv2d channel scales: splits at int(0.6/0.7/0.8/0.9 * out_c)
__device__ __forceinline__ float slim16(const float* w, int o) {
    if (o < 9)  return 1.0f;
    if (o < 11) return w[1];
    if (o < 12) return w[2];
    if (o < 14) return w[3];
    return w[4];
}
__device__ __forceinline__ float slim64(const float* w, int o) {
    if (o < 38) return 1.0f;
    if (o < 44) return w[1];
    if (o < 51) return w[2];
    if (o < 57) return w[3];
    return w[4];
}

// ---- prep: x_t transpose, A_full, packed weights, biases, BN, zero sacc -----
__global__ void prep_kernel(const float* __restrict__ x,   __bf16* __restrict__ xt,
                            const float* __restrict__ wv,  const float* __restrict__ A,
                            const float* __restrict__ PA,  const float* __restrict__ Wd,
                            const float* __restrict__ bd,  const float* __restrict__ WT1,
                            const float* __restrict__ bT1, const float* __restrict__ WT2,
                            const float* __restrict__ bT2, const float* __restrict__ gam,
                            const float* __restrict__ bet, const float* __restrict__ mu,
                            const float* __restrict__ var, float* __restrict__ ws)
{
    const int gid = blockIdx.x * blockDim.x + threadIdx.x;
    const int stride = gridDim.x * blockDim.x;
    // x_t[n][tt][v][c] bf16, zero halo rows. chunk = 8 c per thread.
    for (int idx = gid; idx < N_ * TP_ * V_ * 8; idx += stride) {
        const int cg = idx & 7;
        const int v  = (idx >> 3) % V_;
        const int tt = (idx / (V_ * 8)) % TP_;
        const int n  = idx / (V_ * 8 * TP_);
        const int t  = tt - 4;
        bf16x8 pk;
        if (t >= 0 && t < T_) {
            const float* gp = x + ((size_t)(n * C_ + cg * 8) * T_ + t) * V_ + v;
#pragma unroll
            for (int jj = 0; jj < 8; ++jj) pk[jj] = (__bf16)gp[(size_t)jj * T_ * V_];
        } else {
#pragma unroll
            for (int jj = 0; jj < 8; ++jj) pk[jj] = (__bf16)0.f;
        }
        *(bf16x8*)&xt[((size_t)(n * TP_ + tt) * V_ + v) * C_ + cg * 8] = pk;
    }
    // zero the atomic S accumulator
    for (int idx = gid; idx < SZ_SACC; idx += stride)
        ws[OFF_SACC + idx] = 0.f;
    // A_full = A + PA + 8A^4 - 4A^2 - 4A + I (elementwise powers)
    for (int idx = gid; idx < S_ * V_ * V_; idx += stride) {
        int uv = idx % (V_ * V_);
        int u = uv / V_, v = uv % V_;
        float a  = A[idx];
        float a2 = a * a;
        ws[OFF_AFULL + idx] = a + PA[idx] + 8.f * a2 * a2 - 4.f * a2 - 4.f * a
                              + (u == v ? 1.f : 0.f);
    }
    // t-conv weights: scaled bf16, layout [i][kt][o32][c]
    {
        __bf16* wtb = (__bf16*)(ws + OFF_WTB);
        for (int idx = gid; idx < S_ * KT_ * 32 * C_; idx += stride) {
            int c  = idx % C_;
            int r  = idx / C_;
            int o  = r % 32;  r /= 32;
            int kt = r % KT_;
            int i  = r / KT_;
            float val;
            if (o < IC_)
                val = slim16(wv, o) * WT1[((i * IC_ + o) * C_ + c) * KT_ + kt];
            else
                val = slim16(wv, o - IC_) * WT2[((i * IC_ + (o - IC_)) * C_ + c) * KT_ + kt];
            wtb[idx] = (__bf16)val;
        }
    }
    // combined scaled t-conv biases [i][o32]
    for (int idx = gid; idx < S_ * 32; idx += stride) {
        int i = idx / 32, o = idx % 32;
        float val = (o < IC_) ? slim16(wv, o) * bT1[i * IC_ + o]
                              : slim16(wv, o - IC_) * bT2[i * IC_ + (o - IC_)];
        ws[OFF_BTC + idx] = val;
    }
    // 1x1 conv weights: scaled bf16, [i][o][c]
    {
        __bf16* wdb = (__bf16*)(ws + OFF_WDB);
        for (int idx = gid; idx < S_ * C_ * C_; idx += stride) {
            int c = idx % C_;
            int o = (idx / C_) % C_;
            int i = idx / (C_ * C_);
            wdb[idx] = (__bf16)(slim64(wv, o) * Wd[(i * C_ + o) * C_ + c]);
        }
    }
    // summed scaled 1x1 bias + BN affine
    for (int idx = gid; idx < C_; idx += stride) {
        float bt = 0.f;
        for (int i = 0; i < S_; ++i) bt += slim64(wv, idx) * bd[i * C_ + idx];
        ws[OFF_BDT + idx] = bt;
        float ba = gam[idx] * rsqrtf(var[idx] + 1e-5f);
        ws[OFF_BNA + idx] = ba;
        ws[OFF_BNB + idx] = bet[idx] - mu[idx] * ba;
    }
}

// ---- kernel A: all 3 subsets' temporal convs + attention partials, fused ----
// Phase 1: implicit-GEMM conv via MFMA; x_t (bf16, c-contiguous) staged via
//   bf16x8 load + ds_write_b128 (LDS linear [600 rows][32 c], conflict-free).
// Phase 2 (per subset): acc (+bias, ->bf16) packed bf16x4 into K-major LDS
//   frags (k = tl*16 + o, KS=266), MFMA S[u,v] partial -> atomicAdd into sacc.
__global__ __launch_bounds__(320) void tconv_att_kernel(
    const __bf16* __restrict__ xt, const __bf16* __restrict__ wt,
    const float* __restrict__ btc, float* __restrict__ sacc)
{
    __shared__ __align__(16) char lds_raw[MROWS * CSTR * 2];   // 38400 B
    __bf16* xs  = (__bf16*)lds_raw;                 // [600][32] conv staging
    __bf16* t1L = (__bf16*)lds_raw;                 // [32][KS_] S-stage (union)
    __bf16* t2L = t1L + 32 * KS_;
    const int tid  = threadIdx.x;
    const int n    = blockIdx.y;
    const int t0   = blockIdx.x * TTM;
    const int wv   = tid >> 6;
    const int lane = tid & 63;
    const int l15  = lane & 15;
    const int quad = lane >> 4;

    f32x4 acc[5][6];
#pragma unroll
    for (int j = 0; j < 5; ++j)
#pragma unroll
        for (int p = 0; p < 6; ++p) acc[j][p] = (f32x4){0.f, 0.f, 0.f, 0.f};

    for (int ch = 0; ch < 2; ++ch) {
        const int c0 = ch * 32;
        __syncthreads();
        // stage: 600 rows x 32 c = 2400 x 16B chunks, vector load + b128 write
        {
            const __bf16* xtb = xt + (size_t)(n * TP_ + t0) * (V_ * C_) + c0;
            for (int idx = tid; idx < MROWS * 4; idx += 320) {
                const int lr = idx >> 2, cg = idx & 3;
                const bf16x8 pk = *(const bf16x8*)&xtb[lr * C_ + cg * 8];
                *(bf16x8*)&xs[idx * 8] = pk;
            }
        }
        __syncthreads();

        for (int kt = 0; kt < KT_; ++kt) {
            bf16x8 a[6];
#pragma unroll
            for (int p = 0; p < 6; ++p) {
                const int i = p >> 1, h = p & 1;
                a[p] = *(const bf16x8*)&wt[((size_t)((i * KT_ + kt) * 32 + h * 16 + l15)) * C_ + c0 + quad * 8];
            }
#pragma unroll
            for (int j = 0; j < 5; ++j) {
                const int r = (wv * 5 + j) * 16 + l15 + V_ * kt;
                const bf16x8 b = *(const bf16x8*)&xs[r * CSTR + quad * 8];
#pragma unroll
                for (int p = 0; p < 6; ++p)
                    acc[j][p] = __builtin_amdgcn_mfma_f32_16x16x32_bf16(a[p], b, acc[j][p], 0, 0, 0);
            }
        }
    }

    // ---- Phase 2: per-subset attention partial S[u,v] over this t-block ----
    for (int i = 0; i < S_; ++i) {
        __syncthreads();   // conv/frag LDS readers done
        // pack acc (+bias) -> K-major frags: t1L[u][tl*16+o], t2L[v][tl*16+o]
#pragma unroll
        for (int j = 0; j < 5; ++j) {
            const int m  = (wv * 5 + j) * 16 + l15;
            const int tl = m / V_;
            const int u  = m % V_;
            const bool valid = (t0 + tl) < T_;
#pragma unroll
            for (int h = 0; h < 2; ++h) {
                bf16x4 pk;
#pragma unroll
                for (int r = 0; r < 4; ++r) {
                    const float val = valid
                        ? (acc[j][i * 2 + h][r] + btc[i * 32 + h * 16 + quad * 4 + r])
                        : 0.f;
                    pk[r] = (__bf16)val;
                }
                *(bf16x4*)((h ? t2L : t1L) + u * KS_ + tl * 16 + quad * 4) = pk;
            }
        }
        __syncthreads();   // frags ready
        if (wv < 4) {
            const int ut = wv >> 1, vt = wv & 1;
            f32x4 sa = (f32x4){0.f, 0.f, 0.f, 0.f};
#pragma unroll
            for (int ks = 0; ks < 8; ++ks) {
                const bf16x8 A = *(const bf16x8*)&t1L[(ut * 16 + l15) * KS_ + ks * 32 + quad * 8];
                const bf16x8 B = *(const bf16x8*)&t2L[(vt * 16 + l15) * KS_ + ks * 32 + quad * 8];
                sa = __builtin_amdgcn_mfma_f32_16x16x32_bf16(A, B, sa, 0, 0, 0);
            }
            float* sp = sacc + ((size_t)i * N_ + n) * (V_ * V_);
#pragma unroll
            for (int r = 0; r < 4; ++r) {
                const int u = ut * 16 + quad * 4 + r;
                const int v = vt * 16 + l15;
                if (u < V_ && v < V_) atomicAdd(&sp[u * V_ + v], sa[r]);
            }
        }
    }
}

// ---- kernel B: scale, softmax over u (axis=-2), add A_full -----------------
__global__ __launch_bounds__(256) void att_softmax_kernel(
    const float* __restrict__ sacc, const float* __restrict__ afull,
    float* __restrict__ a1o)
{
    __shared__ float Ss[V_ * V_];
    const int n = blockIdx.x;
    const int i = blockIdx.y;
    const int tid = threadIdx.x;
    for (int p = tid; p < V_ * V_; p += 256)
        Ss[p] = sacc[((size_t)i * N_ + n) * (V_ * V_) + p] * (1.0f / (IC_ * T_));
    __syncthreads();
    if (tid < V_) {
        const int v = tid;
        float m = -1e30f;
#pragma unroll
        for (int u = 0; u < V_; ++u) m = fmaxf(m, Ss[u * V_ + v]);
        float e[V_]; float es = 0.f;
#pragma unroll
        for (int u = 0; u < V_; ++u) { e[u] = expf(Ss[u * V_ + v] - m); es += e[u]; }
        const float inv = 1.0f / es;
#pragma unroll
        for (int u = 0; u < V_; ++u)
            a1o[((size_t)i * N_ + n) * (V_ * V_) + u * V_ + v]
                = afull[i * (V_ * V_) + u * V_ + v] + e[u] * inv;
    }
}

// ---- kernel C: fused (x@A1_i)->1x1 conv via 2-stage MFMA, +BN+res+relu ------
__global__ __launch_bounds__(320) void agg_out_mfma_kernel(
    const float* __restrict__ x,   const float* __restrict__ a1,
    const __bf16* __restrict__ wdb, const float* __restrict__ bdt,
    const float* __restrict__ bna, const float* __restrict__ bnb,
    float* __restrict__ out)
{
    __shared__ __align__(16) __bf16 ags[400 * ASTR];      // 28.8 KB
    __shared__ __align__(16) __bf16 a1t3[S_ * 32 * 32];   // 6 KB [i][v32][u32]
    const int tid  = threadIdx.x;
    const int n    = blockIdx.y;
    const int t0   = blockIdx.x * TTZ;
    const int wv   = tid >> 6;
    const int lane = tid & 63;
    const int l15  = lane & 15;
    const int quad = lane >> 4;

    // stage A1^T for all 3 subsets once: a1t3[i][v][u], zero-padded
    for (int idx = tid; idx < S_ * 1024; idx += 320) {
        const int i = idx >> 10;
        const int r = idx & 1023;
        const int v = r >> 5, u = r & 31;
        float val = (v < V_ && u < V_)
                  ? a1[((size_t)(i * N_ + n) * V_ + u) * V_ + v] : 0.f;
        a1t3[idx] = (__bf16)val;
    }

    f32x4 acc[5][4];
#pragma unroll
    for (int j = 0; j < 5; ++j)
#pragma unroll
        for (int ot = 0; ot < 4; ++ot) acc[j][ot] = (f32x4){0.f, 0.f, 0.f, 0.f};

    const int tg = t0 + l15;                 // GEMM1 A-row (this lane's t)
    for (int chunk = 0; chunk < 2; ++chunk) {
        const int c0 = chunk * 32;
        // load & hold this wave's GEMM1 A-frags (x rows -> bf16), reused for all i
        bf16x8 afr[7];
#pragma unroll
        for (int k = 0; k < 7; ++k) {
            const int c = wv + 5 * k;
            bf16x8 pk;
#pragma unroll
            for (int jj = 0; jj < 8; ++jj) pk[jj] = (__bf16)0.f;
            if (c < 32 && tg < T_) {
                const float* gp = x + ((size_t)(n * C_ + c0 + c) * T_ + tg) * V_;
#pragma unroll
                for (int jj = 0; jj < 8; ++jj) {
                    const int u = quad * 8 + jj;
                    if (u < V_) pk[jj] = (__bf16)gp[u];
                }
            }
            afr[k] = pk;
        }
        for (int i = 0; i < S_; ++i) {
            __syncthreads();   // a1t3 ready (first pass) / prev GEMM2 done with ags
            const bf16x8 b0 = *(const bf16x8*)&a1t3[i * 1024 + l15 * 32 + quad * 8];
            const bf16x8 b1 = *(const bf16x8*)&a1t3[i * 1024 + (16 + l15) * 32 + quad * 8];
            // GEMM1: D row = t-local (quad*4+r), col = v (l15) -> scatter to ags[m2][c]
#pragma unroll
            for (int k = 0; k < 7; ++k) {
                const int c = wv + 5 * k;
                if (c < 32) {
                    f32x4 d0 = (f32x4){0.f, 0.f, 0.f, 0.f};
                    f32x4 d1 = (f32x4){0.f, 0.f, 0.f, 0.f};
                    d0 = __builtin_amdgcn_mfma_f32_16x16x32_bf16(afr[k], b0, d0, 0, 0, 0);
                    d1 = __builtin_amdgcn_mfma_f32_16x16x32_bf16(afr[k], b1, d1, 0, 0, 0);
#pragma unroll
                    for (int r = 0; r < 4; ++r) {
                        const int tl = quad * 4 + r;
                        ags[(tl * V_ + l15) * ASTR + c] = (__bf16)d0[r];
                        if (l15 < V_ - 16)
                            ags[(tl * V_ + 16 + l15) * ASTR + c] = (__bf16)d1[r];
                    }
                }
            }
            __syncthreads();   // ags ready
            // GEMM2: A = ags rows (m2 = l15-indexed), B = wdb (o = l15-indexed)
            bf16x8 bw[4];
#pragma unroll
            for (int ot = 0; ot < 4; ++ot)
                bw[ot] = *(const bf16x8*)&wdb[(size_t)(i * C_ + ot * 16 + l15) * C_ + c0 + quad * 8];
#pragma unroll
            for (int j = 0; j < 5; ++j) {
                const int m2 = (wv * 5 + j) * 16 + l15;
                const bf16x4 lo = *(const bf16x4*)&ags[m2 * ASTR + quad * 8];
                const bf16x4 hi = *(const bf16x4*)&ags[m2 * ASTR + quad * 8 + 4];
                const bf16x8 am = __builtin_shufflevector(lo, hi, 0, 1, 2, 3, 4, 5, 6, 7);
#pragma unroll
                for (int ot = 0; ot < 4; ++ot)
                    acc[j][ot] = __builtin_amdgcn_mfma_f32_16x16x32_bf16(am, bw[ot], acc[j][ot], 0, 0, 0);
            }
        }
    }

    // epilogue: D row = m2 local (quad*4+r consecutive), col = o (l15)
    const int mrem = (T_ - t0) * V_;   // valid m2 range in this t-block
#pragma unroll
    for (int ot = 0; ot < 4; ++ot) {
        const int o  = ot * 16 + l15;
        const float ba = bna[o], bb = bnb[o], bt = bdt[o];
#pragma unroll
        for (int j = 0; j < 5; ++j) {
            const int m2b = (wv * 5 + j) * 16 + quad * 4;
            if (m2b + 3 < mrem) {
                const size_t gi = (size_t)(n * C_ + o) * (T_ * V_) + (size_t)t0 * V_ + m2b;
                const f32x4 xr = *(const f32x4*)&x[gi];
                f32x4 rs;
#pragma unroll
                for (int r = 0; r < 4; ++r)
                    rs[r] = fmaxf(fmaf(acc[j][ot][r] + bt, ba, bb) + xr[r], 0.f);
                *(f32x4*)&out[gi] = rs;
            }
        }
    }
}

// ---- launch ----------------------------------------------------------------
extern "C" void kernel_launch(void* const* d_in, const int* in_sizes, int n_in,
                              void* d_out, int out_size, void* d_ws, size_t ws_size,
                              hipStream_t stream)
{
    (void)in_sizes; (void)n_in; (void)out_size; (void)ws_size;
    const float* x    = (const float*)d_in[0];
    const float* wv   = (const float*)d_in[1];
    const float* A    = (const float*)d_in[2];
    const float* PA   = (const float*)d_in[3];
    const float* Wd   = (const float*)d_in[4];
    const float* bd   = (const float*)d_in[5];
    const float* WT1  = (const float*)d_in[6];
    const float* bT1  = (const float*)d_in[7];
    const float* WT2  = (const float*)d_in[8];
    const float* bT2  = (const float*)d_in[9];
    const float* gam  = (const float*)d_in[10];
    const float* bet  = (const float*)d_in[11];
    const float* mu   = (const float*)d_in[12];
    const float* var  = (const float*)d_in[13];
    float* ws  = (float*)d_ws;
    float* out = (float*)d_out;

    // x_t bf16 scratch lives in d_out (63.9 MB < out's 122.9 MB); consumed by
    // tconv_att before agg_out overwrites out with the final result.
    __bf16* xt = (__bf16*)d_out;

    prep_kernel<<<dim3(15600), dim3(256), 0, stream>>>(
        x, xt, wv, A, PA, Wd, bd, WT1, bT1, WT2, bT2, gam, bet, mu, var, ws);

    tconv_att_kernel<<<dim3(NTB, N_), dim3(320), 0, stream>>>(
        xt, (const __bf16*)(ws + OFF_WTB), ws + OFF_BTC, ws + OFF_SACC);

    att_softmax_kernel<<<dim3(N_, S_), dim3(256), 0, stream>>>(
        ws + OFF_SACC, ws + OFF_AFULL, ws + OFF_A1);

    agg_out_mfma_kernel<<<dim3(NTBZ, N_), dim3(320), 0, stream>>>(
        x, ws + OFF_A1, (const __bf16*)(ws + OFF_WDB),
        ws + OFF_BDT, ws + OFF_BNA, ws + OFF_BNB, out);
}